// Round 1
// baseline (749.305 us; speedup 1.0000x reference)
//
#include <hip/hip_runtime.h>
#include <cstdint>
#include <cstddef>

#define INF_  128
#define OUTF  64
#define ALPHA 0.2f
#define LN_EPS 1e-5f

// ---------------- GEMM: h = x @ W^T + b, sl = h@a_l, sr = h@a_r ----------------
__global__ __launch_bounds__(256) void gemm_kernel(
    const float* __restrict__ x, const float* __restrict__ W,
    const float* __restrict__ b, const float* __restrict__ a,
    float* __restrict__ h, float* __restrict__ sl, float* __restrict__ sr, int n)
{
    __shared__ float Wl[OUTF][INF_ + 4];   // +4 pad: lane-strided b128 reads spread banks
    __shared__ float xs[4][8][INF_];       // per-wave 8 staged x rows

    const int tid  = threadIdx.x;
    const int lane = tid & 63;
    const int wv   = tid >> 6;

    for (int idx = tid; idx < OUTF * INF_; idx += 256) {
        int o = idx >> 7, k = idx & 127;
        Wl[o][k] = W[idx];
    }
    __syncthreads();

    const float bb = b[lane];
    const float al = a[lane];
    const float ar = a[OUTF + lane];

    const int ngroups = (n + 31) >> 5;     // 32 nodes per block-iteration
    for (int g = blockIdx.x; g < ngroups; g += gridDim.x) {
        const int node0 = g * 32 + wv * 8;
        // stage 8 rows (512 B each) of x, coalesced float4
        for (int t = lane; t < 8 * 32; t += 64) {
            int r = t >> 5, q = t & 31;
            int nd = node0 + r; if (nd >= n) nd = 0;
            ((float4*)(&xs[wv][r][0]))[q] = ((const float4*)x)[(size_t)nd * 32 + q];
        }
        __syncthreads();

        float acc[8];
        #pragma unroll
        for (int r = 0; r < 8; r++) acc[r] = bb;

        #pragma unroll 4
        for (int kq = 0; kq < 32; kq++) {
            float4 wq = *(const float4*)&Wl[lane][kq * 4];
            #pragma unroll
            for (int r = 0; r < 8; r++) {
                float4 xq = *(const float4*)&xs[wv][r][kq * 4];   // 16B broadcast
                acc[r] += wq.x * xq.x + wq.y * xq.y + wq.z * xq.z + wq.w * xq.w;
            }
        }

        #pragma unroll
        for (int r = 0; r < 8; r++) {
            const int node = node0 + r;
            const float v = acc[r];
            float p = v * al, q = v * ar;
            for (int s = 32; s; s >>= 1) {
                p += __shfl_down(p, s);
                q += __shfl_down(q, s);
            }
            if (node < n) {
                h[(size_t)node * OUTF + lane] = v;
                if (lane == 0) { sl[node] = p; sr[node] = q; }
            }
        }
        __syncthreads();
    }
}

// ---------------- CSR build ----------------
__global__ void hist_kernel(const int* __restrict__ src, int* __restrict__ cnt, int E)
{
    for (int e = blockIdx.x * blockDim.x + threadIdx.x; e < E; e += gridDim.x * blockDim.x)
        atomicAdd(&cnt[src[e]], 1);
}

__global__ __launch_bounds__(1024) void scan_kernel(
    const int* __restrict__ cnt, int* __restrict__ off, int n)
{
    __shared__ int part[1024];
    const int tid   = threadIdx.x;
    const int chunk = (n + 1023) >> 10;
    const int lo    = tid * chunk;
    const int hi    = min(lo + chunk, n);

    int s = 0;
    for (int i = lo; i < hi; i++) s += cnt[i];
    part[tid] = s;
    __syncthreads();
    for (int d = 1; d < 1024; d <<= 1) {
        int v = (tid >= d) ? part[tid - d] : 0;
        __syncthreads();
        part[tid] += v;
        __syncthreads();
    }
    int base = (tid == 0) ? 0 : part[tid - 1];
    for (int i = lo; i < hi; i++) { off[i] = base; base += cnt[i]; }
    if (tid == 1023) off[n] = part[1023];
}

__global__ void scatter_kernel(const int* __restrict__ src, const int* __restrict__ dst,
                               const int* __restrict__ off, int* __restrict__ cur,
                               int* __restrict__ bdst, int E)
{
    for (int e = blockIdx.x * blockDim.x + threadIdx.x; e < E; e += gridDim.x * blockDim.x) {
        int s = src[e];
        int p = atomicAdd(&cur[s], 1);
        bdst[off[s] + p] = dst[e];
    }
}

// ---------------- Gather + LayerNorm + ELU (one wave per node) ----------------
__global__ __launch_bounds__(256) void gather_kernel(
    const float* __restrict__ h, const float* __restrict__ sl, const float* __restrict__ sr,
    const int* __restrict__ off, const int* __restrict__ bdst,
    const float* __restrict__ gamma, const float* __restrict__ beta,
    float* __restrict__ out, int n)
{
    const int lane = threadIdx.x & 63;
    const int wave = (int)((blockIdx.x * blockDim.x + threadIdx.x) >> 6);
    const int nw   = (int)((gridDim.x * blockDim.x) >> 6);
    const float gm = gamma[lane], bt = beta[lane];

    for (int i = wave; i < n; i += nw) {
        const int o0 = off[i], o1 = off[i + 1];
        const float sli = sl[i];
        float acc = 0.f;

        for (int base = o0; base < o1; base += 64) {
            const int j = base + lane;
            int d = 0; float w = 0.f;
            if (j < o1) {
                d = bdst[j];
                const float sc = sli + sr[d];
                const float lr = sc > 0.f ? sc : ALPHA * sc;
                w = expf(-lr);
            }
            const int m = min(64, o1 - base);
            int t = 0;
            for (; t + 3 < m; t += 4) {        // batch 4 independent gathers
                int   d0 = __shfl(d, t),   d1 = __shfl(d, t+1),
                      d2 = __shfl(d, t+2), d3 = __shfl(d, t+3);
                float w0 = __shfl(w, t),   w1 = __shfl(w, t+1),
                      w2 = __shfl(w, t+2), w3 = __shfl(w, t+3);
                float h0 = h[(size_t)d0 * OUTF + lane];
                float h1 = h[(size_t)d1 * OUTF + lane];
                float h2 = h[(size_t)d2 * OUTF + lane];
                float h3 = h[(size_t)d3 * OUTF + lane];
                acc += w0 * h0; acc += w1 * h1; acc += w2 * h2; acc += w3 * h3;
            }
            for (; t < m; t++) {
                int   dt = __shfl(d, t);
                float wt = __shfl(w, t);
                acc += wt * h[(size_t)dt * OUTF + lane];
            }
        }

        // LayerNorm over the 64 features (biased variance), then ELU
        float mu = acc;
        for (int s = 32; s; s >>= 1) mu += __shfl_xor(mu, s);
        mu *= (1.f / 64.f);
        const float dv = acc - mu;
        float vv = dv * dv;
        for (int s = 32; s; s >>= 1) vv += __shfl_xor(vv, s);
        vv *= (1.f / 64.f);
        const float y = dv * rsqrtf(vv + LN_EPS) * gm + bt;
        out[(size_t)i * OUTF + lane] = y > 0.f ? y : expm1f(y);
    }
}

// ---------------- launch ----------------
extern "C" void kernel_launch(void* const* d_in, const int* in_sizes, int n_in,
                              void* d_out, int out_size, void* d_ws, size_t ws_size,
                              hipStream_t stream)
{
    const float* x     = (const float*)d_in[0];
    const int*   edge  = (const int*)  d_in[1];
    const float* W     = (const float*)d_in[2];
    const float* b     = (const float*)d_in[3];
    const float* a     = (const float*)d_in[4];
    const float* gamma = (const float*)d_in[5];
    const float* beta  = (const float*)d_in[6];
    float* out = (float*)d_out;

    const int n = in_sizes[0] / INF_;   // 100000
    const int E = in_sizes[1] / 2;      // 3200000
    const int* src = edge;
    const int* dst = edge + E;

    char* ws = (char*)d_ws;
    size_t offb = 0;
    auto alloc = [&](size_t bytes) -> void* {
        void* p = ws + offb;
        offb = (offb + bytes + 255) & ~(size_t)255;
        return p;
    };
    float* h    = (float*)alloc((size_t)n * OUTF * 4);
    float* sl   = (float*)alloc((size_t)n * 4);
    float* sr   = (float*)alloc((size_t)n * 4);
    int*   cnt  = (int*)  alloc((size_t)n * 4);
    int*   cur  = (int*)  alloc((size_t)n * 4);
    int*   off  = (int*)  alloc((size_t)(n + 1) * 4);
    int*   bdst = (int*)  alloc((size_t)E * 4);

    // zero histogram + cursor (adjacent slots)
    hipMemsetAsync(cnt, 0, (size_t)((char*)off - (char*)cnt), stream);

    hipLaunchKernelGGL(hist_kernel,    dim3(4096), dim3(256),  0, stream, src, cnt, E);
    hipLaunchKernelGGL(scan_kernel,    dim3(1),    dim3(1024), 0, stream, cnt, off, n);
    hipLaunchKernelGGL(scatter_kernel, dim3(4096), dim3(256),  0, stream, src, dst, off, cur, bdst, E);
    hipLaunchKernelGGL(gemm_kernel,    dim3(1024), dim3(256),  0, stream, x, W, b, a, h, sl, sr, n);
    hipLaunchKernelGGL(gather_kernel,  dim3(2048), dim3(256),  0, stream, h, sl, sr, off, bdst, gamma, beta, out, n);
}

// Round 2
// 570.796 us; speedup vs baseline: 1.3127x; 1.3127x over previous
//
#include <hip/hip_runtime.h>
#include <cstdint>
#include <cstddef>

#define INF_  128
#define OUTF  64
#define ALPHA 0.2f
#define LN_EPS 1e-5f
#define SCB   256     // nodes per scan block

// ---------------- GEMM: h = x @ W^T + b, sl = h@a_l, sr = h@a_r ----------------
__global__ __launch_bounds__(256) void gemm_kernel(
    const float* __restrict__ x, const float* __restrict__ W,
    const float* __restrict__ b, const float* __restrict__ a,
    float* __restrict__ h, float* __restrict__ sl, float* __restrict__ sr, int n)
{
    // Wq[kq][o] = W[o][4kq..4kq+3]; lane reads Wq[kq][lane]: 16B-stride b128,
    // conflict-free (old [o][k] layout was lane-stride 132 floats = 8-way conflict)
    __shared__ float4 Wq[32][64];          // 32 KiB
    __shared__ float4 xs[4][8][32];        // per-wave 8 staged x rows, 16 KiB

    const int tid  = threadIdx.x;
    const int lane = tid & 63;
    const int wv   = tid >> 6;

    for (int idx = tid; idx < 2048; idx += 256) {
        int kq = idx >> 6, o = idx & 63;         // LDS write conflict-free; global
        Wq[kq][o] = ((const float4*)W)[o * 32 + kq];  // read L2-served, one-time
    }
    __syncthreads();

    const float bb = b[lane];
    const float al = a[lane];
    const float ar = a[OUTF + lane];

    const int ngroups = (n + 31) >> 5;     // 32 nodes per block-iteration
    for (int g = blockIdx.x; g < ngroups; g += gridDim.x) {
        const int node0 = g * 32 + wv * 8;
        for (int t = lane; t < 8 * 32; t += 64) {
            int r = t >> 5, q = t & 31;
            int nd = node0 + r; if (nd >= n) nd = 0;
            xs[wv][r][q] = ((const float4*)x)[(size_t)nd * 32 + q];
        }
        __syncthreads();

        float acc[8];
        #pragma unroll
        for (int r = 0; r < 8; r++) acc[r] = bb;

        #pragma unroll 4
        for (int kq = 0; kq < 32; kq++) {
            const float4 wq = Wq[kq][lane];
            #pragma unroll
            for (int r = 0; r < 8; r++) {
                const float4 xq = xs[wv][r][kq];   // same-addr broadcast (free)
                acc[r] = fmaf(wq.x, xq.x, acc[r]);
                acc[r] = fmaf(wq.y, xq.y, acc[r]);
                acc[r] = fmaf(wq.z, xq.z, acc[r]);
                acc[r] = fmaf(wq.w, xq.w, acc[r]);
            }
        }

        #pragma unroll
        for (int r = 0; r < 8; r++) {
            const int node = node0 + r;
            const float v = acc[r];
            float p = v * al, q = v * ar;
            for (int s = 32; s; s >>= 1) {
                p += __shfl_down(p, s);
                q += __shfl_down(q, s);
            }
            if (node < n) {
                h[(size_t)node * OUTF + lane] = v;
                if (lane == 0) { sl[node] = p; sr[node] = q; }
            }
        }
        __syncthreads();
    }
}

// ---------------- CSR build, XCD-partitioned by src range ----------------
// block b serves partition b&7 (round-robin block->XCD heuristic): all writes/
// atomics for a partition stay in one XCD's L2 -> no cross-XCD partial-line flush.
__global__ __launch_bounds__(256) void hist_kernel(
    const int* __restrict__ src, int* __restrict__ cnt, int E, int n)
{
    const int part = blockIdx.x & 7;
    const int bseq = blockIdx.x >> 3;
    const int nseq = gridDim.x >> 3;
    const int psz  = (n + 7) >> 3;
    const int lo = part * psz;
    const int hi = min(n, lo + psz);
    for (int e = bseq * 256 + (int)threadIdx.x; e < E; e += nseq * 256) {
        int s = src[e];
        if (s >= lo && s < hi) atomicAdd(&cnt[s], 1);
    }
}

__global__ __launch_bounds__(256) void scan_a(
    const int* __restrict__ cnt, int* __restrict__ bsum, int n)
{
    __shared__ int red[SCB];
    const int j = blockIdx.x;
    const int i = j * SCB + threadIdx.x;
    red[threadIdx.x] = (i < n) ? cnt[i] : 0;
    __syncthreads();
    for (int d = SCB / 2; d; d >>= 1) {
        if ((int)threadIdx.x < d) red[threadIdx.x] += red[threadIdx.x + d];
        __syncthreads();
    }
    if (threadIdx.x == 0) bsum[j] = red[0];
}

__global__ __launch_bounds__(1024) void scan_b(
    const int* __restrict__ bsum, int* __restrict__ bbase, int nb)
{
    __shared__ int part[1024];
    const int t = threadIdx.x;
    const int own = (t < nb) ? bsum[t] : 0;
    part[t] = own;
    __syncthreads();
    for (int d = 1; d < 1024; d <<= 1) {
        int v = (t >= d) ? part[t - d] : 0;
        __syncthreads();
        part[t] += v;
        __syncthreads();
    }
    if (t < nb) bbase[t] = part[t] - own;       // exclusive
    if (t == nb - 1) bbase[nb] = part[t];       // total = E
}

__global__ __launch_bounds__(256) void scan_c(
    const int* __restrict__ cnt, const int* __restrict__ bbase,
    int* __restrict__ off, int n, int nb)
{
    __shared__ int sc[SCB];
    const int j = blockIdx.x;
    const int i = j * SCB + threadIdx.x;
    const int v = (i < n) ? cnt[i] : 0;
    sc[threadIdx.x] = v;
    __syncthreads();
    for (int d = 1; d < SCB; d <<= 1) {
        int t = ((int)threadIdx.x >= d) ? sc[threadIdx.x - d] : 0;
        __syncthreads();
        sc[threadIdx.x] += t;
        __syncthreads();
    }
    if (i < n) off[i] = bbase[j] + sc[threadIdx.x] - v;   // exclusive scan
    if (j == nb - 1 && threadIdx.x == 0) off[n] = bbase[nb];
}

__global__ __launch_bounds__(256) void scatter_kernel(
    const int* __restrict__ src, const int* __restrict__ dst,
    const int* __restrict__ off, int* __restrict__ cur,
    int* __restrict__ bdst, int E, int n)
{
    const int part = blockIdx.x & 7;
    const int bseq = blockIdx.x >> 3;
    const int nseq = gridDim.x >> 3;
    const int psz  = (n + 7) >> 3;
    const int lo = part * psz;
    const int hi = min(n, lo + psz);
    for (int e = bseq * 256 + (int)threadIdx.x; e < E; e += nseq * 256) {
        int s = src[e];
        if (s >= lo && s < hi) {
            int p = atomicAdd(&cur[s], 1);
            bdst[off[s] + p] = dst[e];      // lands in this XCD's 1.6MB slice
        }
    }
}

// ---------------- Gather + LayerNorm + ELU (one wave per node) ----------------
__global__ __launch_bounds__(256) void gather_kernel(
    const float* __restrict__ h, const float* __restrict__ sl, const float* __restrict__ sr,
    const int* __restrict__ off, const int* __restrict__ bdst,
    const float* __restrict__ gamma, const float* __restrict__ beta,
    float* __restrict__ out, int n)
{
    const int lane = threadIdx.x & 63;
    const int wave = (int)((blockIdx.x * blockDim.x + threadIdx.x) >> 6);
    const int nw   = (int)((gridDim.x * blockDim.x) >> 6);
    const float gm = gamma[lane], bt = beta[lane];

    for (int i = wave; i < n; i += nw) {
        const int o0 = off[i], o1 = off[i + 1];
        const float sli = sl[i];
        float acc = 0.f;

        for (int base = o0; base < o1; base += 64) {
            const int j = base + lane;
            int d = 0; float w = 0.f;
            if (j < o1) {
                d = bdst[j];
                const float sc = sli + sr[d];      // sr is 400KB -> L2-resident
                const float lr = sc > 0.f ? sc : ALPHA * sc;
                w = __expf(-lr);
            }
            const int m = min(64, o1 - base);
            int t = 0;
            for (; t + 3 < m; t += 4) {            // 4 independent gathers in flight
                int   d0 = __shfl(d, t),   d1 = __shfl(d, t+1),
                      d2 = __shfl(d, t+2), d3 = __shfl(d, t+3);
                float w0 = __shfl(w, t),   w1 = __shfl(w, t+1),
                      w2 = __shfl(w, t+2), w3 = __shfl(w, t+3);
                float h0 = h[(size_t)d0 * OUTF + lane];
                float h1 = h[(size_t)d1 * OUTF + lane];
                float h2 = h[(size_t)d2 * OUTF + lane];
                float h3 = h[(size_t)d3 * OUTF + lane];
                acc = fmaf(w0, h0, acc); acc = fmaf(w1, h1, acc);
                acc = fmaf(w2, h2, acc); acc = fmaf(w3, h3, acc);
            }
            for (; t < m; t++) {
                int   dt = __shfl(d, t);
                float wt = __shfl(w, t);
                acc = fmaf(wt, h[(size_t)dt * OUTF + lane], acc);
            }
        }

        float mu = acc;
        for (int s = 32; s; s >>= 1) mu += __shfl_xor(mu, s);
        mu *= (1.f / 64.f);
        const float dv = acc - mu;
        float vv = dv * dv;
        for (int s = 32; s; s >>= 1) vv += __shfl_xor(vv, s);
        vv *= (1.f / 64.f);
        const float y = dv * rsqrtf(vv + LN_EPS) * gm + bt;
        out[(size_t)i * OUTF + lane] = y > 0.f ? y : expm1f(y);
    }
}

// ---------------- launch ----------------
extern "C" void kernel_launch(void* const* d_in, const int* in_sizes, int n_in,
                              void* d_out, int out_size, void* d_ws, size_t ws_size,
                              hipStream_t stream)
{
    const float* x     = (const float*)d_in[0];
    const int*   edge  = (const int*)  d_in[1];
    const float* W     = (const float*)d_in[2];
    const float* b     = (const float*)d_in[3];
    const float* a     = (const float*)d_in[4];
    const float* gamma = (const float*)d_in[5];
    const float* beta  = (const float*)d_in[6];
    float* out = (float*)d_out;

    const int n = in_sizes[0] / INF_;   // 100000
    const int E = in_sizes[1] / 2;      // 3200000
    const int* src = edge;
    const int* dst = edge + E;
    const int nb = (n + SCB - 1) / SCB; // 391 scan blocks (<=1024)

    char* ws = (char*)d_ws;
    size_t offb = 0;
    auto alloc = [&](size_t bytes) -> void* {
        void* p = ws + offb;
        offb = (offb + bytes + 255) & ~(size_t)255;
        return p;
    };
    float* h     = (float*)alloc((size_t)n * OUTF * 4);
    float* sl    = (float*)alloc((size_t)n * 4);
    float* sr    = (float*)alloc((size_t)n * 4);
    int*   cnt   = (int*)  alloc((size_t)n * 4);
    int*   cur   = (int*)  alloc((size_t)n * 4);
    int*   off   = (int*)  alloc((size_t)(n + 1) * 4);
    int*   bsum  = (int*)  alloc((size_t)nb * 4);
    int*   bbase = (int*)  alloc((size_t)(nb + 1) * 4);
    int*   bdst  = (int*)  alloc((size_t)E * 4);

    hipMemsetAsync(cnt, 0, (size_t)((char*)off - (char*)cnt), stream);

    hipLaunchKernelGGL(hist_kernel,    dim3(2048), dim3(256),  0, stream, src, cnt, E, n);
    hipLaunchKernelGGL(scan_a,         dim3(nb),   dim3(SCB),  0, stream, cnt, bsum, n);
    hipLaunchKernelGGL(scan_b,         dim3(1),    dim3(1024), 0, stream, bsum, bbase, nb);
    hipLaunchKernelGGL(scan_c,         dim3(nb),   dim3(SCB),  0, stream, cnt, bbase, off, n, nb);
    hipLaunchKernelGGL(scatter_kernel, dim3(2048), dim3(256),  0, stream, src, dst, off, cur, bdst, E, n);
    hipLaunchKernelGGL(gemm_kernel,    dim3(1024), dim3(256),  0, stream, x, W, b, a, h, sl, sr, n);
    hipLaunchKernelGGL(gather_kernel,  dim3(4096), dim3(256),  0, stream, h, sl, sr, off, bdst, gamma, beta, out, n);
}

// Round 3
// 478.404 us; speedup vs baseline: 1.5663x; 1.1931x over previous
//
#include <hip/hip_runtime.h>
#include <cstdint>
#include <cstddef>

#define INF_  128
#define OUTF  64
#define ALPHA 0.2f
#define LN_EPS 1e-5f
#define SCB   256     // nodes per scan block

// ---------------- GEMM: h = x @ W^T + b, sl = h@a_l, sr = h@a_r ----------------
__global__ __launch_bounds__(256) void gemm_kernel(
    const float* __restrict__ x, const float* __restrict__ W,
    const float* __restrict__ b, const float* __restrict__ a,
    float* __restrict__ h, float* __restrict__ sl, float* __restrict__ sr, int n)
{
    __shared__ float4 Wq[32][64];          // Wq[kq][o]: lane-stride 16B, conflict-free
    __shared__ float4 xs[4][8][32];

    const int tid  = threadIdx.x;
    const int lane = tid & 63;
    const int wv   = tid >> 6;

    for (int idx = tid; idx < 2048; idx += 256) {
        int kq = idx >> 6, o = idx & 63;
        Wq[kq][o] = ((const float4*)W)[o * 32 + kq];
    }
    __syncthreads();

    const float bb = b[lane];
    const float al = a[lane];
    const float ar = a[OUTF + lane];

    const int ngroups = (n + 31) >> 5;
    for (int g = blockIdx.x; g < ngroups; g += gridDim.x) {
        const int node0 = g * 32 + wv * 8;
        for (int t = lane; t < 8 * 32; t += 64) {
            int r = t >> 5, q = t & 31;
            int nd = node0 + r; if (nd >= n) nd = 0;
            xs[wv][r][q] = ((const float4*)x)[(size_t)nd * 32 + q];
        }
        __syncthreads();

        float acc[8];
        #pragma unroll
        for (int r = 0; r < 8; r++) acc[r] = bb;

        #pragma unroll 4
        for (int kq = 0; kq < 32; kq++) {
            const float4 wq = Wq[kq][lane];
            #pragma unroll
            for (int r = 0; r < 8; r++) {
                const float4 xq = xs[wv][r][kq];
                acc[r] = fmaf(wq.x, xq.x, acc[r]);
                acc[r] = fmaf(wq.y, xq.y, acc[r]);
                acc[r] = fmaf(wq.z, xq.z, acc[r]);
                acc[r] = fmaf(wq.w, xq.w, acc[r]);
            }
        }

        #pragma unroll
        for (int r = 0; r < 8; r++) {
            const int node = node0 + r;
            const float v = acc[r];
            float p = v * al, q = v * ar;
            for (int s = 32; s; s >>= 1) {
                p += __shfl_down(p, s);
                q += __shfl_down(q, s);
            }
            if (node < n) {
                h[(size_t)node * OUTF + lane] = v;
                if (lane == 0) { sl[node] = p; sr[node] = q; }
            }
        }
        __syncthreads();
    }
}

// ---------------- CSR build ----------------
// Pass 1: count + per-edge rank in one atomic (return value is free).
// rank store is coalesced fire-and-forget; no dependent chain.
__global__ __launch_bounds__(256) void hist_rank_kernel(
    const int* __restrict__ src, int* __restrict__ cnt,
    int* __restrict__ rank, int E)
{
    for (int e = blockIdx.x * 256 + (int)threadIdx.x; e < E; e += gridDim.x * 256)
        rank[e] = atomicAdd(&cnt[src[e]], 1);
}

__global__ __launch_bounds__(256) void scan_a(
    const int* __restrict__ cnt, int* __restrict__ bsum, int n)
{
    __shared__ int red[SCB];
    const int j = blockIdx.x;
    const int i = j * SCB + threadIdx.x;
    red[threadIdx.x] = (i < n) ? cnt[i] : 0;
    __syncthreads();
    for (int d = SCB / 2; d; d >>= 1) {
        if ((int)threadIdx.x < d) red[threadIdx.x] += red[threadIdx.x + d];
        __syncthreads();
    }
    if (threadIdx.x == 0) bsum[j] = red[0];
}

__global__ __launch_bounds__(1024) void scan_b(
    const int* __restrict__ bsum, int* __restrict__ bbase, int nb)
{
    __shared__ int part[1024];
    const int t = threadIdx.x;
    const int own = (t < nb) ? bsum[t] : 0;
    part[t] = own;
    __syncthreads();
    for (int d = 1; d < 1024; d <<= 1) {
        int v = (t >= d) ? part[t - d] : 0;
        __syncthreads();
        part[t] += v;
        __syncthreads();
    }
    if (t < nb) bbase[t] = part[t] - own;
    if (t == nb - 1) bbase[nb] = part[t];
}

__global__ __launch_bounds__(256) void scan_c(
    const int* __restrict__ cnt, const int* __restrict__ bbase,
    int* __restrict__ off, int n, int nb)
{
    __shared__ int sc[SCB];
    const int j = blockIdx.x;
    const int i = j * SCB + threadIdx.x;
    const int v = (i < n) ? cnt[i] : 0;
    sc[threadIdx.x] = v;
    __syncthreads();
    for (int d = 1; d < SCB; d <<= 1) {
        int t = ((int)threadIdx.x >= d) ? sc[threadIdx.x - d] : 0;
        __syncthreads();
        sc[threadIdx.x] += t;
        __syncthreads();
    }
    if (i < n) off[i] = bbase[j] + sc[threadIdx.x] - v;
    if (j == nb - 1 && threadIdx.x == 0) off[n] = bbase[nb];
}

// Pass 2: atomic-free scatter. All loads coalesced except off[s] (400KB, L2-hot);
// the random store has no dependents -> fully pipelined.
__global__ __launch_bounds__(256) void scatter_kernel(
    const int* __restrict__ src, const int* __restrict__ dst,
    const int* __restrict__ off, const int* __restrict__ rank,
    int* __restrict__ bdst, int E)
{
    for (int e = blockIdx.x * 256 + (int)threadIdx.x; e < E; e += gridDim.x * 256) {
        const int s = src[e];
        bdst[off[s] + rank[e]] = dst[e];
    }
}

// ---------------- Gather + LayerNorm + ELU (one wave per node) ----------------
__global__ __launch_bounds__(256) void gather_kernel(
    const float* __restrict__ h, const float* __restrict__ sl, const float* __restrict__ sr,
    const int* __restrict__ off, const int* __restrict__ bdst,
    const float* __restrict__ gamma, const float* __restrict__ beta,
    float* __restrict__ out, int n)
{
    const int lane = threadIdx.x & 63;
    const int wave = (int)((blockIdx.x * blockDim.x + threadIdx.x) >> 6);
    const int nw   = (int)((gridDim.x * blockDim.x) >> 6);
    const float gm = gamma[lane], bt = beta[lane];

    for (int i = wave; i < n; i += nw) {
        const int o0 = off[i], o1 = off[i + 1];
        const float sli = sl[i];
        float acc = 0.f;

        for (int base = o0; base < o1; base += 64) {
            const int j = base + lane;
            int d = 0; float w = 0.f;
            if (j < o1) {
                d = bdst[j];
                const float sc = sli + sr[d];
                const float lr = sc > 0.f ? sc : ALPHA * sc;
                w = __expf(-lr);
            }
            const int m = min(64, o1 - base);
            int t = 0;
            for (; t + 3 < m; t += 4) {
                int   d0 = __shfl(d, t),   d1 = __shfl(d, t+1),
                      d2 = __shfl(d, t+2), d3 = __shfl(d, t+3);
                float w0 = __shfl(w, t),   w1 = __shfl(w, t+1),
                      w2 = __shfl(w, t+2), w3 = __shfl(w, t+3);
                float h0 = h[(size_t)d0 * OUTF + lane];
                float h1 = h[(size_t)d1 * OUTF + lane];
                float h2 = h[(size_t)d2 * OUTF + lane];
                float h3 = h[(size_t)d3 * OUTF + lane];
                acc = fmaf(w0, h0, acc); acc = fmaf(w1, h1, acc);
                acc = fmaf(w2, h2, acc); acc = fmaf(w3, h3, acc);
            }
            for (; t < m; t++) {
                int   dt = __shfl(d, t);
                float wt = __shfl(w, t);
                acc = fmaf(wt, h[(size_t)dt * OUTF + lane], acc);
            }
        }

        float mu = acc;
        for (int s = 32; s; s >>= 1) mu += __shfl_xor(mu, s);
        mu *= (1.f / 64.f);
        const float dv = acc - mu;
        float vv = dv * dv;
        for (int s = 32; s; s >>= 1) vv += __shfl_xor(vv, s);
        vv *= (1.f / 64.f);
        const float y = dv * rsqrtf(vv + LN_EPS) * gm + bt;
        out[(size_t)i * OUTF + lane] = y > 0.f ? y : expm1f(y);
    }
}

// ---------------- launch ----------------
extern "C" void kernel_launch(void* const* d_in, const int* in_sizes, int n_in,
                              void* d_out, int out_size, void* d_ws, size_t ws_size,
                              hipStream_t stream)
{
    const float* x     = (const float*)d_in[0];
    const int*   edge  = (const int*)  d_in[1];
    const float* W     = (const float*)d_in[2];
    const float* b     = (const float*)d_in[3];
    const float* a     = (const float*)d_in[4];
    const float* gamma = (const float*)d_in[5];
    const float* beta  = (const float*)d_in[6];
    float* out = (float*)d_out;

    const int n = in_sizes[0] / INF_;   // 100000
    const int E = in_sizes[1] / 2;      // 3200000
    const int* src = edge;
    const int* dst = edge + E;
    const int nb = (n + SCB - 1) / SCB; // 391 scan blocks

    char* ws = (char*)d_ws;
    size_t offb = 0;
    auto alloc = [&](size_t bytes) -> void* {
        void* p = ws + offb;
        offb = (offb + bytes + 255) & ~(size_t)255;
        return p;
    };
    float* h     = (float*)alloc((size_t)n * OUTF * 4);
    float* sl    = (float*)alloc((size_t)n * 4);
    float* sr    = (float*)alloc((size_t)n * 4);
    int*   cnt   = (int*)  alloc((size_t)n * 4);
    int*   off   = (int*)  alloc((size_t)(n + 1) * 4);
    int*   bsum  = (int*)  alloc((size_t)nb * 4);
    int*   bbase = (int*)  alloc((size_t)(nb + 1) * 4);
    int*   rank  = (int*)  alloc((size_t)E * 4);
    int*   bdst  = (int*)  alloc((size_t)E * 4);

    hipMemsetAsync(cnt, 0, (size_t)n * 4, stream);

    hipLaunchKernelGGL(hist_rank_kernel, dim3(2048), dim3(256),  0, stream, src, cnt, rank, E);
    hipLaunchKernelGGL(scan_a,           dim3(nb),   dim3(SCB),  0, stream, cnt, bsum, n);
    hipLaunchKernelGGL(scan_b,           dim3(1),    dim3(1024), 0, stream, bsum, bbase, nb);
    hipLaunchKernelGGL(scan_c,           dim3(nb),   dim3(SCB),  0, stream, cnt, bbase, off, n, nb);
    hipLaunchKernelGGL(scatter_kernel,   dim3(2048), dim3(256),  0, stream, src, dst, off, rank, bdst, E);
    hipLaunchKernelGGL(gemm_kernel,      dim3(1024), dim3(256),  0, stream, x, W, b, a, h, sl, sr, n);
    hipLaunchKernelGGL(gather_kernel,    dim3(4096), dim3(256),  0, stream, h, sl, sr, off, bdst, gamma, beta, out, n);
}

// Round 4
// 401.966 us; speedup vs baseline: 1.8641x; 1.1902x over previous
//
#include <hip/hip_runtime.h>
#include <cstdint>
#include <cstddef>

#define INF_  128
#define OUTF  64
#define ALPHA 0.2f
#define LN_EPS 1e-5f

#define NB    1024        // coarse buckets (src >> 7)
#define LOCB  7           // 128 local nodes per bucket
#define NBLK  512         // edge-partition blocks for count/scatter passes

// ---------------- GEMM: h = x @ W^T + b, sl = h@a_l, sr = h@a_r ----------------
__global__ __launch_bounds__(256) void gemm_kernel(
    const float* __restrict__ x, const float* __restrict__ W,
    const float* __restrict__ b, const float* __restrict__ a,
    float* __restrict__ h, float* __restrict__ sl, float* __restrict__ sr, int n)
{
    __shared__ float4 Wq[32][64];          // Wq[kq][o]: lane-stride 16B, conflict-free
    __shared__ float4 xs[4][8][32];

    const int tid  = threadIdx.x;
    const int lane = tid & 63;
    const int wv   = tid >> 6;

    for (int idx = tid; idx < 2048; idx += 256) {
        int kq = idx >> 6, o = idx & 63;
        Wq[kq][o] = ((const float4*)W)[o * 32 + kq];
    }
    __syncthreads();

    const float bb = b[lane];
    const float al = a[lane];
    const float ar = a[OUTF + lane];

    const int ngroups = (n + 31) >> 5;
    for (int g = blockIdx.x; g < ngroups; g += gridDim.x) {
        const int node0 = g * 32 + wv * 8;
        for (int t = lane; t < 8 * 32; t += 64) {
            int r = t >> 5, q = t & 31;
            int nd = node0 + r; if (nd >= n) nd = 0;
            xs[wv][r][q] = ((const float4*)x)[(size_t)nd * 32 + q];
        }
        __syncthreads();

        float acc[8];
        #pragma unroll
        for (int r = 0; r < 8; r++) acc[r] = bb;

        #pragma unroll 4
        for (int kq = 0; kq < 32; kq++) {
            const float4 wq = Wq[kq][lane];
            #pragma unroll
            for (int r = 0; r < 8; r++) {
                const float4 xq = xs[wv][r][kq];
                acc[r] = fmaf(wq.x, xq.x, acc[r]);
                acc[r] = fmaf(wq.y, xq.y, acc[r]);
                acc[r] = fmaf(wq.z, xq.z, acc[r]);
                acc[r] = fmaf(wq.w, xq.w, acc[r]);
            }
        }

        #pragma unroll
        for (int r = 0; r < 8; r++) {
            const int node = node0 + r;
            const float v = acc[r];
            float p = v * al, q = v * ar;
            for (int s = 32; s; s >>= 1) {
                p += __shfl_down(p, s);
                q += __shfl_down(q, s);
            }
            if (node < n) {
                h[(size_t)node * OUTF + lane] = v;
                if (lane == 0) { sl[node] = p; sr[node] = q; }
            }
        }
        __syncthreads();
    }
}

// ---------------- CSR build: coarse radix by src>>7, LDS atomics only ----------------
// Pass 1: per-block LDS histogram over its contiguous chunk -> M[block][bucket]
__global__ __launch_bounds__(256) void count_coarse(
    const int* __restrict__ src, int* __restrict__ M, int E)
{
    __shared__ int hist[NB];
    for (int i = threadIdx.x; i < NB; i += 256) hist[i] = 0;
    __syncthreads();
    const int chunk = (E + NBLK - 1) / NBLK;
    const int lo = blockIdx.x * chunk;
    const int hi = min(E, lo + chunk);
    for (int e = lo + (int)threadIdx.x; e < hi; e += 256)
        atomicAdd(&hist[src[e] >> LOCB], 1);
    __syncthreads();
    for (int i = threadIdx.x; i < NB; i += 256)
        M[blockIdx.x * NB + i] = hist[i];
}

// colsum[B] = sum_b M[b][B]
__global__ __launch_bounds__(256) void colsum_kernel(
    const int* __restrict__ M, int* __restrict__ colsum)
{
    const int B = blockIdx.x * 256 + (int)threadIdx.x;   // 0..NB-1
    int s = 0;
    for (int b = 0; b < NBLK; b++) s += M[b * NB + B];
    colsum[B] = s;
}

// exclusive scan of colsum -> bbase[0..NB], bbase[NB] = E
__global__ __launch_bounds__(1024) void scan_bucket(
    const int* __restrict__ colsum, int* __restrict__ bbase)
{
    __shared__ int part[NB];
    const int t = threadIdx.x;
    const int own = colsum[t];
    part[t] = own;
    __syncthreads();
    for (int d = 1; d < NB; d <<= 1) {
        int v = (t >= d) ? part[t - d] : 0;
        __syncthreads();
        part[t] += v;
        __syncthreads();
    }
    bbase[t] = part[t] - own;
    if (t == NB - 1) bbase[NB] = part[t];
}

// M[b][B] <- bbase[B] + prefix_b M[b][B]  (per-(block,bucket) write base)
__global__ __launch_bounds__(256) void rowbase_kernel(
    int* __restrict__ M, const int* __restrict__ bbase)
{
    const int B = blockIdx.x * 256 + (int)threadIdx.x;
    int run = bbase[B];
    for (int b = 0; b < NBLK; b++) {
        int c = M[b * NB + B];
        M[b * NB + B] = run;
        run += c;
    }
}

// Pass 2: place edges into coarse buckets via LDS cursors. pk = (src&127)<<17 | dst
__global__ __launch_bounds__(256) void scatter_coarse(
    const int* __restrict__ src, const int* __restrict__ dst,
    const int* __restrict__ M, int* __restrict__ pk, int E)
{
    __shared__ int cur[NB];
    for (int i = threadIdx.x; i < NB; i += 256) cur[i] = M[blockIdx.x * NB + i];
    __syncthreads();
    const int chunk = (E + NBLK - 1) / NBLK;
    const int lo = blockIdx.x * chunk;
    const int hi = min(E, lo + chunk);
    for (int e = lo + (int)threadIdx.x; e < hi; e += 256) {
        const int s = src[e];
        const int p = atomicAdd(&cur[s >> LOCB], 1);
        pk[p] = ((s & 127) << 17) | dst[e];      // dst < 2^17
    }
}

// Pass 3: one block per bucket -> exact per-node CSR (off, bdst), all in LDS/L2
__global__ __launch_bounds__(256) void finalize_kernel(
    const int* __restrict__ pk, const int* __restrict__ bbase,
    int* __restrict__ off, int* __restrict__ bdst, int n, int E)
{
    __shared__ int lhist[128];
    __shared__ int sc[256];
    __shared__ int cur2[128];

    const int B  = blockIdx.x;
    const int b0 = bbase[B], b1 = bbase[B + 1];
    const int t  = threadIdx.x;

    if (t < 128) lhist[t] = 0;
    __syncthreads();
    for (int j = b0 + t; j < b1; j += 256)
        atomicAdd(&lhist[pk[j] >> 17], 1);
    __syncthreads();

    // inclusive scan over 256 lanes (entries >=128 are 0)
    const int v = (t < 128) ? lhist[t] : 0;
    sc[t] = v;
    __syncthreads();
    for (int d = 1; d < 256; d <<= 1) {
        int u = (t >= d) ? sc[t - d] : 0;
        __syncthreads();
        sc[t] += u;
        __syncthreads();
    }
    if (t < 128) {
        const int base = b0 + sc[t] - v;     // exclusive
        const int s = (B << LOCB) + t;
        if (s < n) off[s] = base;
        cur2[t] = base;
    }
    if (B == 0 && t == 0) off[n] = E;
    __syncthreads();

    for (int j = b0 + t; j < b1; j += 256) {
        const int w = pk[j];
        const int p = atomicAdd(&cur2[w >> 17], 1);
        bdst[p] = w & 0x1FFFF;
    }
}

// ---------------- Gather + LayerNorm + ELU (one wave per node) ----------------
__global__ __launch_bounds__(256) void gather_kernel(
    const float* __restrict__ h, const float* __restrict__ sl, const float* __restrict__ sr,
    const int* __restrict__ off, const int* __restrict__ bdst,
    const float* __restrict__ gamma, const float* __restrict__ beta,
    float* __restrict__ out, int n)
{
    const int lane = threadIdx.x & 63;
    const int wave = (int)((blockIdx.x * blockDim.x + threadIdx.x) >> 6);
    const int nw   = (int)((gridDim.x * blockDim.x) >> 6);
    const float gm = gamma[lane], bt = beta[lane];

    for (int i = wave; i < n; i += nw) {
        const int o0 = off[i], o1 = off[i + 1];
        const float sli = sl[i];
        float acc = 0.f;

        for (int base = o0; base < o1; base += 64) {
            const int j = base + lane;
            int d = 0; float w = 0.f;
            if (j < o1) {
                d = bdst[j];
                const float sc = sli + sr[d];
                const float lr = sc > 0.f ? sc : ALPHA * sc;
                w = __expf(-lr);
            }
            const int m = min(64, o1 - base);
            int t = 0;
            for (; t + 3 < m; t += 4) {
                int   d0 = __shfl(d, t),   d1 = __shfl(d, t+1),
                      d2 = __shfl(d, t+2), d3 = __shfl(d, t+3);
                float w0 = __shfl(w, t),   w1 = __shfl(w, t+1),
                      w2 = __shfl(w, t+2), w3 = __shfl(w, t+3);
                float h0 = h[(size_t)d0 * OUTF + lane];
                float h1 = h[(size_t)d1 * OUTF + lane];
                float h2 = h[(size_t)d2 * OUTF + lane];
                float h3 = h[(size_t)d3 * OUTF + lane];
                acc = fmaf(w0, h0, acc); acc = fmaf(w1, h1, acc);
                acc = fmaf(w2, h2, acc); acc = fmaf(w3, h3, acc);
            }
            for (; t < m; t++) {
                int   dt = __shfl(d, t);
                float wt = __shfl(w, t);
                acc = fmaf(wt, h[(size_t)dt * OUTF + lane], acc);
            }
        }

        float mu = acc;
        for (int s = 32; s; s >>= 1) mu += __shfl_xor(mu, s);
        mu *= (1.f / 64.f);
        const float dv = acc - mu;
        float vv = dv * dv;
        for (int s = 32; s; s >>= 1) vv += __shfl_xor(vv, s);
        vv *= (1.f / 64.f);
        const float y = dv * rsqrtf(vv + LN_EPS) * gm + bt;
        out[(size_t)i * OUTF + lane] = y > 0.f ? y : expm1f(y);
    }
}

// ---------------- launch ----------------
extern "C" void kernel_launch(void* const* d_in, const int* in_sizes, int n_in,
                              void* d_out, int out_size, void* d_ws, size_t ws_size,
                              hipStream_t stream)
{
    const float* x     = (const float*)d_in[0];
    const int*   edge  = (const int*)  d_in[1];
    const float* W     = (const float*)d_in[2];
    const float* b     = (const float*)d_in[3];
    const float* a     = (const float*)d_in[4];
    const float* gamma = (const float*)d_in[5];
    const float* beta  = (const float*)d_in[6];
    float* out = (float*)d_out;

    const int n = in_sizes[0] / INF_;   // 100000
    const int E = in_sizes[1] / 2;      // 3200000
    const int* src = edge;
    const int* dst = edge + E;
    const int nbuck = (n + 127) >> 7;   // 782 used buckets

    char* ws = (char*)d_ws;
    size_t offb = 0;
    auto alloc = [&](size_t bytes) -> void* {
        void* p = ws + offb;
        offb = (offb + bytes + 255) & ~(size_t)255;
        return p;
    };
    float* h      = (float*)alloc((size_t)n * OUTF * 4);
    float* sl     = (float*)alloc((size_t)n * 4);
    float* sr     = (float*)alloc((size_t)n * 4);
    int*   M      = (int*)  alloc((size_t)NBLK * NB * 4);   // 2 MB
    int*   colsum = (int*)  alloc((size_t)NB * 4);
    int*   bbase  = (int*)  alloc((size_t)(NB + 1) * 4);
    int*   off    = (int*)  alloc((size_t)(n + 1) * 4);
    int*   pk     = (int*)  alloc((size_t)E * 4);
    int*   bdst   = (int*)  alloc((size_t)E * 4);

    hipMemsetAsync(M, 0, (size_t)NBLK * NB * 4, stream);

    hipLaunchKernelGGL(count_coarse,    dim3(NBLK),   dim3(256),  0, stream, src, M, E);
    hipLaunchKernelGGL(colsum_kernel,   dim3(NB/256), dim3(256),  0, stream, M, colsum);
    hipLaunchKernelGGL(scan_bucket,     dim3(1),      dim3(1024), 0, stream, colsum, bbase);
    hipLaunchKernelGGL(rowbase_kernel,  dim3(NB/256), dim3(256),  0, stream, M, bbase);
    hipLaunchKernelGGL(scatter_coarse,  dim3(NBLK),   dim3(256),  0, stream, src, dst, M, pk, E);
    hipLaunchKernelGGL(finalize_kernel, dim3(nbuck),  dim3(256),  0, stream, pk, bbase, off, bdst, n, E);
    hipLaunchKernelGGL(gemm_kernel,     dim3(1024),   dim3(256),  0, stream, x, W, b, a, h, sl, sr, n);
    hipLaunchKernelGGL(gather_kernel,   dim3(4096),   dim3(256),  0, stream, h, sl, sr, off, bdst, gamma, beta, out, n);
}